// Round 1
// baseline (472.373 us; speedup 1.0000x reference)
//
#include <hip/hip_runtime.h>

#define B 16
#define C 128
#define NN 1024
#define KV 512
#define CHO 4

// ---------------- K1: projections  f = Wq X, g = Wk X, hvT[n][k] = (Wv X)^T
__global__ __launch_bounds__(256) void proj_kernel(
    const float* __restrict__ x, const float* __restrict__ Wq,
    const float* __restrict__ Wk, const float* __restrict__ Wv,
    float* __restrict__ f, float* __restrict__ g, float* __restrict__ hvT)
{
  const int nt = blockIdx.x, rt = blockIdx.y, b = blockIdx.z;
  const int r0 = rt * 64, n0 = nt * 64;
  __shared__ __align__(16) float Wt[64][132];
  __shared__ __align__(16) float Xt[128][68];
  const int t = threadIdx.x;

  const float* Wbase; int roff;
  if (r0 < 128)      { Wbase = Wq; roff = r0; }
  else if (r0 < 256) { Wbase = Wk; roff = r0 - 128; }
  else               { Wbase = Wv; roff = r0 - 256; }

  // W tile: 64 rows x 128 k   (2048 float4 / 256 thr = 8 each)
  #pragma unroll
  for (int i = 0; i < 8; ++i) {
    int idx = t + i * 256;
    int row = idx >> 5, c4 = (idx & 31) * 4;
    float4 v = *reinterpret_cast<const float4*>(Wbase + (size_t)(roff + row) * C + c4);
    *reinterpret_cast<float4*>(&Wt[row][c4]) = v;
  }
  // X tile: 128 k x 64 n
  #pragma unroll
  for (int i = 0; i < 8; ++i) {
    int idx = t + i * 256;
    int row = idx >> 4, c4 = (idx & 15) * 4;
    float4 v = *reinterpret_cast<const float4*>(x + (size_t)(b * C + row) * NN + n0 + c4);
    *reinterpret_cast<float4*>(&Xt[row][c4]) = v;
  }
  __syncthreads();

  const int tr = t >> 4, tc = t & 15;   // 16x16 threads, 4x4 outputs each
  float acc[4][4];
  #pragma unroll
  for (int i = 0; i < 4; ++i)
    #pragma unroll
    for (int j = 0; j < 4; ++j) acc[i][j] = 0.f;

  for (int k = 0; k < C; k += 4) {
    float4 wv[4], xv[4];
    #pragma unroll
    for (int i = 0; i < 4; ++i) wv[i] = *reinterpret_cast<const float4*>(&Wt[tr * 4 + i][k]);
    #pragma unroll
    for (int kk = 0; kk < 4; ++kk) xv[kk] = *reinterpret_cast<const float4*>(&Xt[k + kk][tc * 4]);
    #pragma unroll
    for (int i = 0; i < 4; ++i) {
      float wi[4] = { wv[i].x, wv[i].y, wv[i].z, wv[i].w };
      #pragma unroll
      for (int kk = 0; kk < 4; ++kk) {
        float xk[4] = { xv[kk].x, xv[kk].y, xv[kk].z, xv[kk].w };
        acc[i][0] += wi[kk] * xk[0];
        acc[i][1] += wi[kk] * xk[1];
        acc[i][2] += wi[kk] * xk[2];
        acc[i][3] += wi[kk] * xk[3];
      }
    }
  }

  if (r0 < 256) {
    float* dst = (r0 < 128) ? f : g;
    int rbase = (r0 < 128) ? r0 : (r0 - 128);
    #pragma unroll
    for (int i = 0; i < 4; ++i) {
      float4 o = { acc[i][0], acc[i][1], acc[i][2], acc[i][3] };
      *reinterpret_cast<float4*>(dst + (size_t)(b * C + rbase + tr * 4 + i) * NN + n0 + tc * 4) = o;
    }
  } else {
    int k0 = r0 - 256 + tr * 4;
    #pragma unroll
    for (int j = 0; j < 4; ++j) {
      float4 o = { acc[0][j], acc[1][j], acc[2][j], acc[3][j] };
      *reinterpret_cast<float4*>(hvT + ((size_t)b * NN + n0 + tc * 4 + j) * KV + k0) = o;
    }
  }
}

// ---------------- K2: fused attention (flash-style, online softmax over n)
__global__ __launch_bounds__(512) void attn_kernel(
    const float* __restrict__ f, const float* __restrict__ g,
    const float* __restrict__ hvT, const float* __restrict__ gamma,
    const float* __restrict__ mask, float* __restrict__ out)
{
  const int mt = blockIdx.x, b = blockIdx.y;
  const int m0 = mt * 64;
  __shared__ __align__(16) float gsT[64][132];  // gsT[m][c] = g[c][m0+m]
  __shared__ __align__(16) float fsT[32][132];  // fsT[n][c] = f[c][n0g+n]
  __shared__ __align__(16) float ps[32][68];    // scores then p
  __shared__ __align__(16) float colmax[64];
  __shared__ __align__(16) float colsum[64];
  __shared__ __align__(16) float resc[64];
  const int t = threadIdx.x;
  const int lane = t & 63, wid = t >> 6;

  #pragma unroll
  for (int i = 0; i < 16; ++i) {
    int idx = t + i * 512;
    int m = idx & 63, c = idx >> 6;
    gsT[m][c] = g[(size_t)(b * C + c) * NN + m0 + m];
  }
  if (t < 64) { colmax[t] = -3.0e38f; colsum[t] = 0.f; }

  float acc[4][16];
  #pragma unroll
  for (int i = 0; i < 4; ++i)
    #pragma unroll
    for (int j = 0; j < 16; ++j) acc[i][j] = 0.f;

  const int oc  = wid * 16 + (lane & 15);   // 0..127
  const int mj0 = (lane >> 4) * 16;         // 0,16,32,48
  const int sn0 = t & 15;                   // scores: rows sn0, sn0+16
  const int sm0 = (t >> 4) * 2;             // scores: cols sm0, sm0+1

  __syncthreads();

  for (int n0g = 0; n0g < NN; n0g += 32) {
    // stage f tile transposed
    #pragma unroll
    for (int i = 0; i < 8; ++i) {
      int idx = t + i * 512;
      int n = idx & 31, c = idx >> 5;
      fsT[n][c] = f[(size_t)(b * C + c) * NN + n0g + n];
    }
    __syncthreads();

    // scores: 2n x 2m per thread
    float d00 = 0.f, d01 = 0.f, d10 = 0.f, d11 = 0.f;
    for (int c = 0; c < C; c += 4) {
      float4 fa = *reinterpret_cast<const float4*>(&fsT[sn0][c]);
      float4 fb = *reinterpret_cast<const float4*>(&fsT[sn0 + 16][c]);
      float4 ga = *reinterpret_cast<const float4*>(&gsT[sm0][c]);
      float4 gb = *reinterpret_cast<const float4*>(&gsT[sm0 + 1][c]);
      d00 += fa.x * ga.x + fa.y * ga.y + fa.z * ga.z + fa.w * ga.w;
      d01 += fa.x * gb.x + fa.y * gb.y + fa.z * gb.z + fa.w * gb.w;
      d10 += fb.x * ga.x + fb.y * ga.y + fb.z * ga.z + fb.w * ga.w;
      d11 += fb.x * gb.x + fb.y * gb.y + fb.z * gb.z + fb.w * gb.w;
    }
    ps[sn0][sm0]      = d00;  ps[sn0][sm0 + 1]      = d01;
    ps[sn0 + 16][sm0] = d10;  ps[sn0 + 16][sm0 + 1] = d11;
    __syncthreads();

    // online softmax stats (wave 0, one column per lane)
    if (t < 64) {
      int m = t;
      float M = colmax[m];
      float tmax = -3.0e38f;
      for (int n = 0; n < 32; ++n) tmax = fmaxf(tmax, ps[n][m]);
      float newM = fmaxf(M, tmax);
      float r = __expf(M - newM);
      float tsum = 0.f;
      for (int n = 0; n < 32; ++n) {
        float p = __expf(ps[n][m] - newM);
        ps[n][m] = p;
        tsum += p;
      }
      colsum[m] = colsum[m] * r + tsum;
      colmax[m] = newM;
      resc[m] = r;
    }
    __syncthreads();

    // rescale accumulator
    {
      float4 ra = *reinterpret_cast<const float4*>(&resc[mj0 + 0]);
      float4 rb = *reinterpret_cast<const float4*>(&resc[mj0 + 4]);
      float4 rc = *reinterpret_cast<const float4*>(&resc[mj0 + 8]);
      float4 rd = *reinterpret_cast<const float4*>(&resc[mj0 + 12]);
      float rr[16] = { ra.x, ra.y, ra.z, ra.w, rb.x, rb.y, rb.z, rb.w,
                       rc.x, rc.y, rc.z, rc.w, rd.x, rd.y, rd.z, rd.w };
      #pragma unroll
      for (int j = 0; j < 16; ++j) {
        acc[0][j] *= rr[j]; acc[1][j] *= rr[j];
        acc[2][j] *= rr[j]; acc[3][j] *= rr[j];
      }
    }

    // PV accumulate
    #pragma unroll 2
    for (int n = 0; n < 32; ++n) {
      const float* hp = hvT + ((size_t)b * NN + n0g + n) * KV + oc;
      float v0 = hp[0], v1 = hp[128], v2 = hp[256], v3 = hp[384];
      float4 p0 = *reinterpret_cast<const float4*>(&ps[n][mj0 + 0]);
      float4 p1 = *reinterpret_cast<const float4*>(&ps[n][mj0 + 4]);
      float4 p2 = *reinterpret_cast<const float4*>(&ps[n][mj0 + 8]);
      float4 p3 = *reinterpret_cast<const float4*>(&ps[n][mj0 + 12]);
      float pvv[16] = { p0.x, p0.y, p0.z, p0.w, p1.x, p1.y, p1.z, p1.w,
                        p2.x, p2.y, p2.z, p2.w, p3.x, p3.y, p3.z, p3.w };
      #pragma unroll
      for (int j = 0; j < 16; ++j) {
        acc[0][j] += v0 * pvv[j];
        acc[1][j] += v1 * pvv[j];
        acc[2][j] += v2 * pvv[j];
        acc[3][j] += v3 * pvv[j];
      }
    }
    __syncthreads();
  }

  // epilogue: gamma * acc / colsum + mask   → out[b][oc][m][ch], float4 over ch
  const float gam = gamma[0];
  float4 sa = *reinterpret_cast<const float4*>(&colsum[mj0 + 0]);
  float4 sb = *reinterpret_cast<const float4*>(&colsum[mj0 + 4]);
  float4 sc = *reinterpret_cast<const float4*>(&colsum[mj0 + 8]);
  float4 sd = *reinterpret_cast<const float4*>(&colsum[mj0 + 12]);
  float sv[16] = { sa.x, sa.y, sa.z, sa.w, sb.x, sb.y, sb.z, sb.w,
                   sc.x, sc.y, sc.z, sc.w, sd.x, sd.y, sd.z, sd.w };
  #pragma unroll
  for (int j = 0; j < 16; ++j) {
    int m = m0 + mj0 + j;
    float inv = 1.0f / sv[j];
    float4 mk = *reinterpret_cast<const float4*>(mask + ((size_t)oc * NN + m) * CHO);
    float4 o;
    o.x = gam * acc[0][j] * inv + mk.x;
    o.y = gam * acc[1][j] * inv + mk.y;
    o.z = gam * acc[2][j] * inv + mk.z;
    o.w = gam * acc[3][j] * inv + mk.w;
    *reinterpret_cast<float4*>(out + ((size_t)(b * C + oc) * NN + m) * CHO) = o;
  }
}

extern "C" void kernel_launch(void* const* d_in, const int* in_sizes, int n_in,
                              void* d_out, int out_size, void* d_ws, size_t ws_size,
                              hipStream_t stream) {
  const float* x     = (const float*)d_in[0];
  const float* Wq    = (const float*)d_in[1];
  const float* Wk    = (const float*)d_in[2];
  const float* Wv    = (const float*)d_in[3];
  const float* gamma = (const float*)d_in[4];
  const float* mask  = (const float*)d_in[5];
  float* out = (float*)d_out;

  float* wsf = (float*)d_ws;
  float* f   = wsf;                            // 16*128*1024
  float* g   = wsf + (size_t)B * C * NN;       // 16*128*1024
  float* hvT = wsf + (size_t)2 * B * C * NN;   // 16*1024*512  (hvT[b][n][k])

  proj_kernel<<<dim3(16, 12, 16), 256, 0, stream>>>(x, Wq, Wk, Wv, f, g, hvT);
  attn_kernel<<<dim3(16, 16), 512, 0, stream>>>(f, g, hvT, gamma, mask, out);
}

// Round 3
// 128.688 us; speedup vs baseline: 3.6707x; 3.6707x over previous
//
#include <hip/hip_runtime.h>

#define B 16
#define C 128
#define NN 1024
#define KV 512
#define CHO 4

typedef _Float16 f16x8 __attribute__((ext_vector_type(8)));
typedef float f32x4 __attribute__((ext_vector_type(4)));

__device__ __forceinline__ unsigned short f2h(float v) {
  _Float16 h = (_Float16)v;
  return __builtin_bit_cast(unsigned short, h);
}
__device__ __forceinline__ unsigned int packh2(float a, float b) {
  return (unsigned int)f2h(a) | ((unsigned int)f2h(b) << 16);
}

// ---------------- K1: projections (fp32 math, f16 stores in MFMA layouts)
//   fT[b][n][c] = (Wq x)^T    gT[b][m][c] = (Wk x)^T    hv[b][k][n] = Wv x
__global__ __launch_bounds__(256) void proj_kernel(
    const float* __restrict__ x, const float* __restrict__ Wq,
    const float* __restrict__ Wk, const float* __restrict__ Wv,
    unsigned short* __restrict__ fT, unsigned short* __restrict__ gT,
    unsigned short* __restrict__ hv)
{
  const int nt = blockIdx.x, rt = blockIdx.y, b = blockIdx.z;
  const int r0 = rt * 64, n0 = nt * 64;
  __shared__ __align__(16) float Wt[64][132];
  __shared__ __align__(16) float Xt[128][68];
  const int t = threadIdx.x;

  const float* Wbase; int roff;
  if (r0 < 128)      { Wbase = Wq; roff = r0; }
  else if (r0 < 256) { Wbase = Wk; roff = r0 - 128; }
  else               { Wbase = Wv; roff = r0 - 256; }

  #pragma unroll
  for (int i = 0; i < 8; ++i) {
    int idx = t + i * 256;
    int row = idx >> 5, c4 = (idx & 31) * 4;
    float4 v = *reinterpret_cast<const float4*>(Wbase + (size_t)(roff + row) * C + c4);
    *reinterpret_cast<float4*>(&Wt[row][c4]) = v;
  }
  #pragma unroll
  for (int i = 0; i < 8; ++i) {
    int idx = t + i * 256;
    int row = idx >> 4, c4 = (idx & 15) * 4;
    float4 v = *reinterpret_cast<const float4*>(x + (size_t)(b * C + row) * NN + n0 + c4);
    *reinterpret_cast<float4*>(&Xt[row][c4]) = v;
  }
  __syncthreads();

  const int tr = t >> 4, tc = t & 15;
  float acc[4][4];
  #pragma unroll
  for (int i = 0; i < 4; ++i)
    #pragma unroll
    for (int j = 0; j < 4; ++j) acc[i][j] = 0.f;

  for (int k = 0; k < C; k += 4) {
    float4 wv[4], xv[4];
    #pragma unroll
    for (int i = 0; i < 4; ++i) wv[i] = *reinterpret_cast<const float4*>(&Wt[tr * 4 + i][k]);
    #pragma unroll
    for (int kk = 0; kk < 4; ++kk) xv[kk] = *reinterpret_cast<const float4*>(&Xt[k + kk][tc * 4]);
    #pragma unroll
    for (int i = 0; i < 4; ++i) {
      float wi[4] = { wv[i].x, wv[i].y, wv[i].z, wv[i].w };
      #pragma unroll
      for (int kk = 0; kk < 4; ++kk) {
        float xk[4] = { xv[kk].x, xv[kk].y, xv[kk].z, xv[kk].w };
        acc[i][0] += wi[kk] * xk[0];
        acc[i][1] += wi[kk] * xk[1];
        acc[i][2] += wi[kk] * xk[2];
        acc[i][3] += wi[kk] * xk[3];
      }
    }
  }

  if (r0 < 256) {
    // transposed f16 store:  dstT[n][c'] ,  c' = roff+tr*4+i, n = n0+tc*4+j
    unsigned short* dst = (r0 < 128) ? fT : gT;
    #pragma unroll
    for (int j = 0; j < 4; ++j) {
      ushort4 o = { f2h(acc[0][j]), f2h(acc[1][j]), f2h(acc[2][j]), f2h(acc[3][j]) };
      *reinterpret_cast<ushort4*>(dst + ((size_t)(b * NN) + n0 + tc * 4 + j) * C + roff + tr * 4) = o;
    }
  } else {
    // normal f16 store: hv[k][n], k = roff+tr*4+i, n = n0+tc*4+j
    #pragma unroll
    for (int i = 0; i < 4; ++i) {
      ushort4 o = { f2h(acc[i][0]), f2h(acc[i][1]), f2h(acc[i][2]), f2h(acc[i][3]) };
      *reinterpret_cast<ushort4*>(hv + ((size_t)(b * KV) + roff + tr * 4 + i) * NN + n0 + tc * 4) = o;
    }
  }
}

// ---------------- K2: MFMA flash attention (fp16 operands, fp32 accum)
// scores[n][m] = sum_c f[c][n] g[c][m]; softmax over n; out[k][m] = sum_n hv[k][n] P[n][m]
// Block: 64 m-columns, 4 waves. Wave w: softmax owner of m-sub w (16 m) AND
// PV owner of k-range [128w, 128w+128). P shared via LDS. ch = k>>7 = w.
__global__ __launch_bounds__(256, 2) void attn_kernel(
    const unsigned short* __restrict__ fT, const unsigned short* __restrict__ gT,
    const unsigned short* __restrict__ hv, const float* __restrict__ gamma,
    const float* __restrict__ mask, float* __restrict__ out)
{
  const int t  = threadIdx.x;
  const int w  = t >> 6;
  const int l  = t & 63;
  const int lg = l >> 4;
  const int lm = l & 15;
  const int b  = blockIdx.y;
  const int m0 = blockIdx.x * 64;

  __shared__ unsigned short P_lds[64][40];   // [m][n] f16, +8 pad
  __shared__ float resc_s[64];
  __shared__ float lsum_s[64];

  // Q frags (loop-invariant): B operand, lane holds gT[m0+16w+lm][c4*32 + 8lg + i]
  f16x8 qf[4];
  {
    const unsigned short* qp = gT + ((size_t)(b * NN) + m0 + 16 * w + lm) * C + lg * 8;
    #pragma unroll
    for (int c4 = 0; c4 < 4; ++c4)
      qf[c4] = *reinterpret_cast<const f16x8*>(qp + c4 * 32);
  }

  f32x4 acc[8][4];  // [kt][mt]: k = 128w+16kt+4lg+reg, m = m0+16mt+lm
  #pragma unroll
  for (int kt = 0; kt < 8; ++kt)
    #pragma unroll
    for (int mt = 0; mt < 4; ++mt)
      acc[kt][mt] = (f32x4){0.f, 0.f, 0.f, 0.f};

  float M = -3.0e38f, Lpart = 0.f;

  const unsigned short* kp = fT + ((size_t)(b * NN) + lm) * C + lg * 8;
  const unsigned short* vp = hv + ((size_t)(b * KV) + 128 * w + lm) * NN + lg * 8;

  #pragma unroll 1
  for (int n0 = 0; n0 < NN; n0 += 32) {
    // V frags early (independent of P; overlap with QK+softmax)
    f16x8 vf[8];
    #pragma unroll
    for (int kt = 0; kt < 8; ++kt)
      vf[kt] = *reinterpret_cast<const f16x8*>(vp + (size_t)(16 * kt) * NN + n0);

    // QK^T (swapped): A = K rows n, B = Q^T cols m -> D[n][m]
    f32x4 st0 = {0.f, 0.f, 0.f, 0.f}, st1 = {0.f, 0.f, 0.f, 0.f};
    #pragma unroll
    for (int c4 = 0; c4 < 4; ++c4) {
      f16x8 k0 = *reinterpret_cast<const f16x8*>(kp + (size_t)(n0)      * C + c4 * 32);
      f16x8 k1 = *reinterpret_cast<const f16x8*>(kp + (size_t)(n0 + 16) * C + c4 * 32);
      st0 = __builtin_amdgcn_mfma_f32_16x16x32_f16(k0, qf[c4], st0, 0, 0, 0);
      st1 = __builtin_amdgcn_mfma_f32_16x16x32_f16(k1, qf[c4], st1, 0, 0, 0);
    }

    // online softmax over n (owner wave for m-sub w); lane holds n = n0 + {0,16} + 4lg + reg
    float cmax = fmaxf(fmaxf(fmaxf(st0.x, st0.y), fmaxf(st0.z, st0.w)),
                       fmaxf(fmaxf(st1.x, st1.y), fmaxf(st1.z, st1.w)));
    cmax = fmaxf(cmax, __shfl_xor(cmax, 16, 64));
    cmax = fmaxf(cmax, __shfl_xor(cmax, 32, 64));
    float r = 1.0f;
    if (!__all(cmax <= M + 8.0f)) {       // T13 defer-rescale
      float newM = fmaxf(M, cmax);
      r = __expf(M - newM);
      M = newM;
      Lpart *= r;
    }
    float p0 = __expf(st0.x - M), p1 = __expf(st0.y - M),
          p2 = __expf(st0.z - M), p3 = __expf(st0.w - M),
          p4 = __expf(st1.x - M), p5 = __expf(st1.y - M),
          p6 = __expf(st1.z - M), p7 = __expf(st1.w - M);
    Lpart += ((p0 + p1) + (p2 + p3)) + ((p4 + p5) + (p6 + p7));
    if (lg == 0) resc_s[16 * w + lm] = r;
    unsigned short* prow = &P_lds[16 * w + lm][0];
    *(unsigned int*)(prow + 4 * lg)          = packh2(p0, p1);
    *(unsigned int*)(prow + 4 * lg + 2)      = packh2(p2, p3);
    *(unsigned int*)(prow + 16 + 4 * lg)     = packh2(p4, p5);
    *(unsigned int*)(prow + 16 + 4 * lg + 2) = packh2(p6, p7);
    __syncthreads();

    // rescale accumulators (rare: T13)
    float rr0 = resc_s[lm], rr1 = resc_s[16 + lm], rr2 = resc_s[32 + lm], rr3 = resc_s[48 + lm];
    if (!__all((rr0 == 1.f) & (rr1 == 1.f) & (rr2 == 1.f) & (rr3 == 1.f))) {
      float rr[4] = { rr0, rr1, rr2, rr3 };
      #pragma unroll
      for (int kt = 0; kt < 8; ++kt)
        #pragma unroll
        for (int mt = 0; mt < 4; ++mt)
          acc[kt][mt] *= rr[mt];
    }

    // P^T B-frags from LDS: lane holds P_lds[16mt+lm][8lg + i]
    f16x8 pt[4];
    #pragma unroll
    for (int mt = 0; mt < 4; ++mt)
      pt[mt] = *reinterpret_cast<const f16x8*>(&P_lds[16 * mt + lm][8 * lg]);

    // PV: A = V^T rows k (hv[k][n] contiguous), B = P^T -> D[k][m]
    #pragma unroll
    for (int kt = 0; kt < 8; ++kt) {
      acc[kt][0] = __builtin_amdgcn_mfma_f32_16x16x32_f16(vf[kt], pt[0], acc[kt][0], 0, 0, 0);
      acc[kt][1] = __builtin_amdgcn_mfma_f32_16x16x32_f16(vf[kt], pt[1], acc[kt][1], 0, 0, 0);
      acc[kt][2] = __builtin_amdgcn_mfma_f32_16x16x32_f16(vf[kt], pt[2], acc[kt][2], 0, 0, 0);
      acc[kt][3] = __builtin_amdgcn_mfma_f32_16x16x32_f16(vf[kt], pt[3], acc[kt][3], 0, 0, 0);
    }
    __syncthreads();
  }

  // final denominators
  float Lp = Lpart;
  Lp += __shfl_xor(Lp, 16, 64);
  Lp += __shfl_xor(Lp, 32, 64);
  if (lg == 0) lsum_s[16 * w + lm] = Lp;
  __syncthreads();

  const float gam = gamma[0];
  float scv[4] = { gam / lsum_s[lm],      gam / lsum_s[16 + lm],
                   gam / lsum_s[32 + lm], gam / lsum_s[48 + lm] };

  // out[b][oc][m][ch] + mask[oc][m][ch];  k = 128w+16kt+4lg+reg -> oc = k&127, ch = w
  #pragma unroll
  for (int kt = 0; kt < 8; ++kt) {
    #pragma unroll
    for (int mt = 0; mt < 4; ++mt) {
      #pragma unroll
      for (int reg = 0; reg < 4; ++reg) {
        int oc = 16 * kt + 4 * lg + reg;
        int m  = m0 + 16 * mt + lm;
        float v = acc[kt][mt][reg] * scv[mt] + mask[((size_t)oc * NN + m) * CHO + w];
        out[(((size_t)(b * 128 + oc)) * NN + m) * CHO + w] = v;
      }
    }
  }
}

extern "C" void kernel_launch(void* const* d_in, const int* in_sizes, int n_in,
                              void* d_out, int out_size, void* d_ws, size_t ws_size,
                              hipStream_t stream) {
  const float* x     = (const float*)d_in[0];
  const float* Wq    = (const float*)d_in[1];
  const float* Wk    = (const float*)d_in[2];
  const float* Wv    = (const float*)d_in[3];
  const float* gamma = (const float*)d_in[4];
  const float* mask  = (const float*)d_in[5];
  float* out = (float*)d_out;

  unsigned short* fT = (unsigned short*)d_ws;                 // [B][NN][C]  f16
  unsigned short* gT = fT + (size_t)B * NN * C;               // [B][NN][C]  f16
  unsigned short* hv = gT + (size_t)B * NN * C;               // [B][KV][NN] f16

  proj_kernel<<<dim3(16, 12, B), 256, 0, stream>>>(x, Wq, Wk, Wv, fT, gT, hv);
  attn_kernel<<<dim3(16, B), 256, 0, stream>>>(fT, gT, hv, gamma, mask, out);
}